// Round 1
// baseline (10054.327 us; speedup 1.0000x reference)
//
#include <hip/hip_runtime.h>
#include <math.h>

// Model constants
#define BATCHN 128
#define LSEQ   32
#define TSTEPS 32
#define AIMG   64
#define CCH    3
// RN == WN == 5, (A-1)/(N-1) = 15.75, (A+1)/2 = 32.5

__device__ __forceinline__ float sigmoidf_(float v){ return 1.f/(1.f+expf(-v)); }

// ---------------------------------------------------------------------------
// Generic NT GEMM: C[m,n] = sum_k A[m*lda+k]*B[n*ldb+k] + b1[n] + b2[n]
// grid = (ceil(M/32), ceil(N/32)), 256 threads
// ---------------------------------------------------------------------------
__global__ void gemm_nt(const float* __restrict__ A, int lda,
                        const float* __restrict__ B, int ldb,
                        const float* __restrict__ bias1, const float* __restrict__ bias2,
                        float* __restrict__ C, int ldc, int M, int N, int K)
{
    __shared__ float As[32][33];
    __shared__ float Bs[32][33];
    const int tid = threadIdx.x;
    const int tile_m = blockIdx.x*32, tile_n = blockIdx.y*32;
    const int tx = tid & 31, ty = tid >> 5;
    float acc[4] = {0.f,0.f,0.f,0.f};
    for (int k0 = 0; k0 < K; k0 += 32) {
        for (int i = tid; i < 1024; i += 256) {
            int rr = i >> 5, cc = i & 31;
            int m = tile_m + rr, k = k0 + cc;
            As[rr][cc] = (m < M && k < K) ? A[(long)m*lda + k] : 0.f;
            int n = tile_n + rr;
            Bs[rr][cc] = (n < N && k < K) ? B[(long)n*ldb + k] : 0.f;
        }
        __syncthreads();
#pragma unroll
        for (int kk = 0; kk < 32; ++kk) {
            float bv = Bs[tx][kk];
            acc[0] += As[ty     ][kk]*bv;
            acc[1] += As[ty +  8][kk]*bv;
            acc[2] += As[ty + 16][kk]*bv;
            acc[3] += As[ty + 24][kk]*bv;
        }
        __syncthreads();
    }
    int n = tile_n + tx;
    if (n < N) {
        float bb = (bias1 ? bias1[n] : 0.f) + (bias2 ? bias2[n] : 0.f);
#pragma unroll
        for (int j = 0; j < 4; ++j) {
            int m = tile_m + ty + 8*j;
            if (m < M) C[(long)m*ldc + n] = acc[j] + bb;
        }
    }
}

// ---------------------------------------------------------------------------
// LSTM gates = A1@B1.T + A2@B2.T + A3@B3.T + bih + bhh   (M=128, N=2048)
// grid = (4, 64), 256 threads
// ---------------------------------------------------------------------------
__global__ void lstm_gates(
    const float* __restrict__ A1, int lda1, const float* __restrict__ B1, int ldb1, int K1,
    const float* __restrict__ A2, int lda2, const float* __restrict__ B2, int ldb2, int K2,
    const float* __restrict__ A3, int lda3, const float* __restrict__ B3, int ldb3, int K3,
    const float* __restrict__ bias1, const float* __restrict__ bias2,
    float* __restrict__ C, int N)
{
    __shared__ float As[32][33];
    __shared__ float Bs[32][33];
    const int tid = threadIdx.x;
    const int tile_m = blockIdx.x*32, tile_n = blockIdx.y*32;
    const int tx = tid & 31, ty = tid >> 5;
    float acc[4] = {0.f,0.f,0.f,0.f};
    const float* Ap[3] = {A1,A2,A3};
    const float* Bp[3] = {B1,B2,B3};
    const int ldAv[3] = {lda1,lda2,lda3};
    const int ldBv[3] = {ldb1,ldb2,ldb3};
    const int Kv[3]   = {K1,K2,K3};
    for (int s = 0; s < 3; ++s) {
        const float* A = Ap[s]; const float* B = Bp[s];
        int lda = ldAv[s], ldb = ldBv[s], K = Kv[s];
        for (int k0 = 0; k0 < K; k0 += 32) {
            for (int i = tid; i < 1024; i += 256) {
                int rr = i >> 5, cc = i & 31;
                int k = k0 + cc;
                int m = tile_m + rr;
                As[rr][cc] = (k < K) ? A[(long)m*lda + k] : 0.f;
                int n = tile_n + rr;
                Bs[rr][cc] = (k < K) ? B[(long)n*ldb + k] : 0.f;
            }
            __syncthreads();
#pragma unroll
            for (int kk = 0; kk < 32; ++kk) {
                float bv = Bs[tx][kk];
                acc[0] += As[ty     ][kk]*bv;
                acc[1] += As[ty +  8][kk]*bv;
                acc[2] += As[ty + 16][kk]*bv;
                acc[3] += As[ty + 24][kk]*bv;
            }
            __syncthreads();
        }
    }
    int n = tile_n + tx;
    float bb = bias1[n] + bias2[n];
#pragma unroll
    for (int j = 0; j < 4; ++j) {
        int m = tile_m + ty + 8*j;
        C[(long)m*N + n] = acc[j] + bb;
    }
}

// ---------------------------------------------------------------------------
// LSTM cell elementwise: gates (128,4H) [i,f,g,o] -> update h,c (128,H)
// ---------------------------------------------------------------------------
__global__ void lstm_cell_k(const float* __restrict__ gates, int H,
                            float* __restrict__ h, float* __restrict__ c)
{
    int idx = blockIdx.x*blockDim.x + threadIdx.x;
    if (idx >= BATCHN*H) return;
    int b = idx / H, u = idx - b*H;
    const float* g = gates + (long)b*4*H;
    float gi = g[u], gf = g[H+u], gg = g[2*H+u], go = g[3*H+u];
    float c2 = sigmoidf_(gf)*c[idx] + sigmoidf_(gi)*tanhf(gg);
    float h2 = sigmoidf_(go)*tanhf(c2);
    c[idx] = c2; h[idx] = h2;
}

// ---------------------------------------------------------------------------
// One step of the bidirectional language LSTM (H=128).
// grid = 256 (128 fwd + 128 bwd), 128 threads. xp includes bih+bhh.
// ---------------------------------------------------------------------------
__global__ void lang_step_k(int s,
    const float* __restrict__ xpf, const float* __restrict__ xpb,
    const float* __restrict__ Whh_f, const float* __restrict__ Whh_b,
    float* __restrict__ hf, float* __restrict__ cf,
    float* __restrict__ hb, float* __restrict__ cb,
    float* __restrict__ hlang)
{
    const int b   = blockIdx.x & 127;
    const int dir = blockIdx.x >> 7;
    const int tid = threadIdx.x;                 // 128 threads
    const int l   = dir ? (31 - s) : s;
    const float* xp  = (dir ? xpb : xpf) + ((long)b*32 + l)*512;
    const float* Whh = dir ? Whh_b : Whh_f;
    float* h = (dir ? hb : hf) + b*128;
    float* c = (dir ? cb : cf) + b*128;
    __shared__ float hs[128];
    __shared__ float gs[512];
    hs[tid] = h[tid];
    __syncthreads();
    for (int j = tid; j < 512; j += 128) {
        float acc = xp[j];
        const float* w = Whh + (long)j*128;
        for (int k = 0; k < 128; ++k) acc += hs[k]*w[k];
        gs[j] = acc;
    }
    __syncthreads();
    float c2 = sigmoidf_(gs[128+tid])*c[tid] + sigmoidf_(gs[tid])*tanhf(gs[256+tid]);
    float h2 = sigmoidf_(gs[384+tid])*tanhf(c2);
    c[tid] = c2; h[tid] = h2;
    hlang[((long)b*32 + l)*256 + dir*128 + tid] = h2;
}

// ---------------------------------------------------------------------------
// Fused: (blocks 0..127) read-attention + glimpse -> r (128,150)
//        (blocks 128..255) alignment + softmax -> sent (128,256)
// Both depend only on h_dec (previous) and precomputed langpre/hlang.
// 256 threads.
// ---------------------------------------------------------------------------
__global__ void attn_glimpse_align_k(
    const float* __restrict__ x,          // (128, 12288)
    const float* __restrict__ h_dec,      // (128, 512)
    const float* __restrict__ attn_W, const float* __restrict__ attn_b,
    const float* __restrict__ align_W1,   // (512, 768)
    const float* __restrict__ align_w2,   // (512)
    const float* __restrict__ langpre,    // (128,32,512) includes b1
    const float* __restrict__ hlang,      // (128,32,256)
    float* __restrict__ r,                // (128,150)
    float* __restrict__ sent)             // (128,256)
{
    const int tid = threadIdx.x;
    __shared__ float red[256];
    __shared__ float sP[5];
    __shared__ float Fx[5][64], Fy[5][64];
    __shared__ float denx[5], deny[5], SFx[5], SFy[5];
    __shared__ float tmp1[3][64][5];
    __shared__ float hs[512];
    __shared__ float dp[512];
    __shared__ float logits[32];
    __shared__ float smv[32];
    __shared__ float ssum;

    if (blockIdx.x < 128) {
        const int b = blockIdx.x;
        const float* hd = h_dec + (long)b*512;
        // p = h_dec @ attn_W.T + attn_b  (5 reductions)
        for (int i = 0; i < 5; ++i) {
            float p = 0.f;
            for (int k = tid; k < 512; k += 256) p += hd[k]*attn_W[i*512+k];
            red[tid] = p; __syncthreads();
            for (int st = 128; st > 0; st >>= 1) { if (tid < st) red[tid] += red[tid+st]; __syncthreads(); }
            if (tid == 0) sP[i] = red[0] + attn_b[i];
            __syncthreads();
        }
        float gx    = 32.5f*(sP[0]+1.f);
        float gy    = 32.5f*(sP[1]+1.f);
        float s2    = expf(sP[2]);
        float delta = 15.75f*expf(sP[3]);
        float gamma = expf(sP[4]);
        for (int p = tid; p < 320; p += 256) {
            int i = p >> 6, a = p & 63;
            float mux = gx + ((float)i - 3.0f)*delta;
            float muy = gy + ((float)i - 3.0f)*delta;
            float dx = (float)a - mux, dy = (float)a - muy;
            Fx[i][a] = expf(-dx*dx/(2.f*s2));
            Fy[i][a] = expf(-dy*dy/(2.f*s2));
        }
        __syncthreads();
        if (tid < 10) {
            int i = tid % 5;
            const float* F = (tid < 5) ? Fx[i] : Fy[i];
            float s = 0.f;
            for (int a = 0; a < 64; ++a) s += F[a];
            if (tid < 5) denx[i] = s + 1e-8f; else deny[i] = s + 1e-8f;
        }
        __syncthreads();
        for (int p = tid; p < 320; p += 256) {
            int i = p >> 6, a = p & 63;
            Fx[i][a] /= denx[i];
            Fy[i][a] /= deny[i];
        }
        __syncthreads();
        if (tid < 10) {
            int i = tid % 5;
            const float* F = (tid < 5) ? Fx[i] : Fy[i];
            float s = 0.f;
            for (int a = 0; a < 64; ++a) s += F[a];
            if (tid < 5) SFx[i] = s; else SFy[i] = s;
        }
        __syncthreads();
        // tmp1[c][y][j] = sum_x img[b,c,y,x]*Fx[j][x]
        for (int p = tid; p < 192; p += 256) {
            int cc = p / 64, yy = p - cc*64;
            const float* row = x + (long)b*12288 + cc*4096 + yy*64;
            float a0=0,a1=0,a2=0,a3=0,a4=0;
            for (int xx = 0; xx < 64; ++xx) {
                float v = row[xx];
                a0 += v*Fx[0][xx]; a1 += v*Fx[1][xx]; a2 += v*Fx[2][xx];
                a3 += v*Fx[3][xx]; a4 += v*Fx[4][xx];
            }
            tmp1[cc][yy][0]=a0; tmp1[cc][yy][1]=a1; tmp1[cc][yy][2]=a2;
            tmp1[cc][yy][3]=a3; tmp1[cc][yy][4]=a4;
        }
        __syncthreads();
        if (tid < 75) {
            int cc = tid/25, i = (tid/5)%5, j = tid%5;
            float g = 0.f;
            for (int yy = 0; yy < 64; ++yy) g += Fy[i][yy]*tmp1[cc][yy][j];
            r[(long)b*150 + tid]      = gamma*g;
            // glimpse(x-0.5) = glimpse(x) - 0.5*SFy[i]*SFx[j]
            r[(long)b*150 + 75 + tid] = gamma*(g - 0.5f*SFy[i]*SFx[j]);
        }
    } else {
        const int b = blockIdx.x - 128;
        const float* hd = h_dec + (long)b*512;
        for (int k = tid; k < 512; k += 256) hs[k] = hd[k];
        __syncthreads();
        // dec part of alignment pre-activation
        for (int a = tid; a < 512; a += 256) {
            const float* w = align_W1 + (long)a*768;
            float acc = 0.f;
            for (int k = 0; k < 512; ++k) acc += hs[k]*w[k];
            dp[a] = acc;
        }
        __syncthreads();
        // logits[l] = sum_a tanh(dp[a]+langpre[b,l,a]) * w2[a]
        {
            int l = tid >> 3, part = tid & 7;
            const float* lp = langpre + ((long)b*32 + l)*512;
            float acc = 0.f;
            int a0 = part*64;
            for (int a = a0; a < a0+64; ++a)
                acc += tanhf(dp[a] + lp[a]) * align_w2[a];
            red[tid] = acc;
        }
        __syncthreads();
        if ((tid & 7) == 0) {
            float s = 0.f;
            for (int p2 = 0; p2 < 8; ++p2) s += red[tid+p2];
            logits[tid >> 3] = s;
        }
        __syncthreads();
        if (tid == 0) {
            float mx = logits[0];
            for (int l = 1; l < 32; ++l) mx = fmaxf(mx, logits[l]);
            float s = 0.f;
            for (int l = 0; l < 32; ++l) { float e = expf(logits[l]-mx); smv[l] = e; s += e; }
            ssum = s;
        }
        __syncthreads();
        {
            int k = tid;  // < 256
            float acc = 0.f;
            for (int l = 0; l < 32; ++l) acc += smv[l]*hlang[((long)b*32 + l)*256 + k];
            sent[(long)b*256 + k] = acc / ssum;
        }
    }
}

// ---------------------------------------------------------------------------
// mu/q: q = h_enc@mu_W.T + mu_b + eps * exp(h_enc@sig_W.T + sig_b)
// grid = 128, 128 threads
// ---------------------------------------------------------------------------
__global__ void mu_q_k(const float* __restrict__ h_enc,
                       const float* __restrict__ mu_W, const float* __restrict__ mu_b,
                       const float* __restrict__ sig_W, const float* __restrict__ sig_b,
                       const float* __restrict__ eps,   // (128,100) slice
                       float* __restrict__ q)
{
    const int b = blockIdx.x, tid = threadIdx.x;
    __shared__ float hs[512];
    for (int k = tid; k < 512; k += 128) hs[k] = h_enc[(long)b*512 + k];
    __syncthreads();
    if (tid < 100) {
        const float* wm = mu_W  + (long)tid*512;
        const float* wsg= sig_W + (long)tid*512;
        float am = 0.f, as = 0.f;
        for (int k = 0; k < 512; ++k) { float h = hs[k]; am += h*wm[k]; as += h*wsg[k]; }
        float mu = am + mu_b[tid];
        float sg = expf(as + sig_b[tid]);
        q[(long)b*100 + tid] = mu + eps[(long)b*100 + tid]*sg;
    }
}

// ---------------------------------------------------------------------------
// Write head: w = h_dec2@write_W.T + write_b (3,5,5); write attention; output.
// grid = 128, 256 threads
// ---------------------------------------------------------------------------
__global__ void write_out_k(const float* __restrict__ h_dec,
                            const float* __restrict__ write_W, const float* __restrict__ write_b,
                            const float* __restrict__ attn_W,  const float* __restrict__ attn_b,
                            float* __restrict__ out)   // (128, 12288) slice
{
    const int b = blockIdx.x, tid = threadIdx.x;
    __shared__ float hs[512];
    __shared__ float red[256];
    __shared__ float sP[5];
    __shared__ float w75[75];
    __shared__ float Fx[5][64], Fy[5][64];
    __shared__ float denx[5], deny[5];
    __shared__ float t2[3][5][64];

    for (int k = tid; k < 512; k += 256) hs[k] = h_dec[(long)b*512 + k];
    __syncthreads();
    for (int i = 0; i < 5; ++i) {
        float p = 0.f;
        for (int k = tid; k < 512; k += 256) p += hs[k]*attn_W[i*512+k];
        red[tid] = p; __syncthreads();
        for (int st = 128; st > 0; st >>= 1) { if (tid < st) red[tid] += red[tid+st]; __syncthreads(); }
        if (tid == 0) sP[i] = red[0] + attn_b[i];
        __syncthreads();
    }
    float gx    = 32.5f*(sP[0]+1.f);
    float gy    = 32.5f*(sP[1]+1.f);
    float s2    = expf(sP[2]);
    float delta = 15.75f*expf(sP[3]);
    float inv_g = 1.f/expf(sP[4]);
    if (tid < 75) {
        const float* w = write_W + (long)tid*512;
        float acc = 0.f;
        for (int k = 0; k < 512; ++k) acc += hs[k]*w[k];
        w75[tid] = acc + write_b[tid];
    }
    for (int p = tid; p < 320; p += 256) {
        int i = p >> 6, a = p & 63;
        float mux = gx + ((float)i - 3.0f)*delta;
        float muy = gy + ((float)i - 3.0f)*delta;
        float dx = (float)a - mux, dy = (float)a - muy;
        Fx[i][a] = expf(-dx*dx/(2.f*s2));
        Fy[i][a] = expf(-dy*dy/(2.f*s2));
    }
    __syncthreads();
    if (tid < 10) {
        int i = tid % 5;
        const float* F = (tid < 5) ? Fx[i] : Fy[i];
        float s = 0.f;
        for (int a = 0; a < 64; ++a) s += F[a];
        if (tid < 5) denx[i] = s + 1e-8f; else deny[i] = s + 1e-8f;
    }
    __syncthreads();
    for (int p = tid; p < 320; p += 256) {
        int i = p >> 6, a = p & 63;
        Fx[i][a] /= denx[i];
        Fy[i][a] /= deny[i];
    }
    __syncthreads();
    // t2[c][i][x] = sum_j w[c,i,j]*Fx[j][x]
    for (int p = tid; p < 960; p += 256) {
        int cc = p / 320, rem = p - cc*320;
        int i = rem / 64, xx = rem - i*64;
        float acc = 0.f;
        for (int j = 0; j < 5; ++j) acc += w75[cc*25 + i*5 + j]*Fx[j][xx];
        t2[cc][i][xx] = acc;
    }
    __syncthreads();
    float* ob = out + (long)b*12288;
    for (int p = tid; p < 12288; p += 256) {
        int cc = p >> 12, yy = (p >> 6) & 63, xx = p & 63;
        float acc = 0.f;
        for (int i = 0; i < 5; ++i) acc += Fy[i][yy]*t2[cc][i][xx];
        ob[p] = acc*inv_g;
    }
}

// ---------------------------------------------------------------------------
extern "C" void kernel_launch(void* const* d_in, const int* in_sizes, int n_in,
                              void* d_out, int out_size, void* d_ws, size_t ws_size,
                              hipStream_t stream)
{
    const float* x        = (const float*)d_in[0];
    const float* y        = (const float*)d_in[1];
    const float* eps_q    = (const float*)d_in[2];
    const float* enc_Wih  = (const float*)d_in[3];
    const float* enc_Whh  = (const float*)d_in[4];
    const float* enc_bih  = (const float*)d_in[5];
    const float* enc_bhh  = (const float*)d_in[6];
    const float* dec_Wih  = (const float*)d_in[7];
    const float* dec_Whh  = (const float*)d_in[8];
    const float* dec_bih  = (const float*)d_in[9];
    const float* dec_bhh  = (const float*)d_in[10];
    const float* mu_W     = (const float*)d_in[11];
    const float* mu_b     = (const float*)d_in[12];
    const float* sig_W    = (const float*)d_in[13];
    const float* sig_b    = (const float*)d_in[14];
    const float* write_W  = (const float*)d_in[15];
    const float* write_b  = (const float*)d_in[16];
    const float* align_W1 = (const float*)d_in[17];
    const float* align_b1 = (const float*)d_in[18];
    const float* align_w2 = (const float*)d_in[19];
    const float* attn_W   = (const float*)d_in[20];
    const float* attn_b   = (const float*)d_in[21];
    const float* lf_Wih   = (const float*)d_in[22];
    const float* lf_Whh   = (const float*)d_in[23];
    const float* lf_bih   = (const float*)d_in[24];
    const float* lf_bhh   = (const float*)d_in[25];
    const float* lb_Wih   = (const float*)d_in[26];
    const float* lb_Whh   = (const float*)d_in[27];
    const float* lb_bih   = (const float*)d_in[28];
    const float* lb_bhh   = (const float*)d_in[29];
    float* out = (float*)d_out;

    float* ws = (float*)d_ws;
    size_t off = 0;
    auto alloc = [&](size_t n) { float* p = ws + off; off += n; return p; };
    float* hlang   = alloc((size_t)128*32*256);   // (B,L,256)
    float* langpre = alloc((size_t)128*32*512);   // h_lang @ W1_lang.T + b1
    float* xpf     = alloc((size_t)128*32*512);   // lang fwd input proj (+biases)
    float* xpb     = alloc((size_t)128*32*512);
    float* gates   = alloc((size_t)128*2048);
    float* rbuf    = alloc((size_t)128*150);
    float* sentb   = alloc((size_t)128*256);
    float* qbuf    = alloc((size_t)128*100);
    float* states  = alloc((size_t)4*128*128 + (size_t)4*128*512);
    float* hf    = states;
    float* cf    = hf   + 128*128;
    float* hb    = cf   + 128*128;
    float* cb    = hb   + 128*128;
    float* h_enc = cb   + 128*128;
    float* c_enc = h_enc + 128*512;
    float* h_dec = c_enc + 128*512;
    float* c_dec = h_dec + 128*512;

    hipMemsetAsync(states, 0, ((size_t)4*128*128 + (size_t)4*128*512)*sizeof(float), stream);

    // Language LSTM input projections (biases folded in)
    gemm_nt<<<dim3(128,16),256,0,stream>>>(y,300, lf_Wih,300, lf_bih, lf_bhh, xpf,512, 4096,512,300);
    gemm_nt<<<dim3(128,16),256,0,stream>>>(y,300, lb_Wih,300, lb_bih, lb_bhh, xpb,512, 4096,512,300);
    for (int s = 0; s < 32; ++s)
        lang_step_k<<<256,128,0,stream>>>(s, xpf, xpb, lf_Whh, lb_Whh, hf, cf, hb, cb, hlang);
    // Language half of alignment pre-activation (time-invariant, hoisted)
    gemm_nt<<<dim3(128,16),256,0,stream>>>(hlang,256, align_W1+512,768, align_b1, nullptr,
                                           langpre,512, 4096,512,256);

    for (int t = 0; t < 32; ++t) {
        attn_glimpse_align_k<<<256,256,0,stream>>>(x, h_dec, attn_W, attn_b,
                                                   align_W1, align_w2, langpre, hlang,
                                                   rbuf, sentb);
        lstm_gates<<<dim3(4,64),256,0,stream>>>(rbuf,150,  enc_Wih,    662,150,
                                                h_dec,512, enc_Wih+150,662,512,
                                                h_enc,512, enc_Whh,    512,512,
                                                enc_bih, enc_bhh, gates, 2048);
        lstm_cell_k<<<256,256,0,stream>>>(gates, 512, h_enc, c_enc);
        mu_q_k<<<128,128,0,stream>>>(h_enc, mu_W, mu_b, sig_W, sig_b,
                                     eps_q + (size_t)t*128*100, qbuf);
        lstm_gates<<<dim3(4,64),256,0,stream>>>(qbuf,100,  dec_Wih,    356,100,
                                                sentb,256, dec_Wih+100,356,256,
                                                h_dec,512, dec_Whh,    512,512,
                                                dec_bih, dec_bhh, gates, 2048);
        lstm_cell_k<<<256,256,0,stream>>>(gates, 512, h_dec, c_dec);
        write_out_k<<<128,256,0,stream>>>(h_dec, write_W, write_b, attn_W, attn_b,
                                          out + (size_t)t*128*12288);
    }
}

// Round 3
// 7072.735 us; speedup vs baseline: 1.4216x; 1.4216x over previous
//
#include <hip/hip_runtime.h>
#include <hip/hip_bf16.h>
#include <math.h>

typedef __attribute__((ext_vector_type(8))) short short8;
typedef __attribute__((ext_vector_type(4))) float floatx4;

__device__ __forceinline__ float sigmoidf_(float v){ return 1.f/(1.f+expf(-v)); }

__device__ __forceinline__ floatx4 mfma16(short8 a, short8 b, floatx4 c) {
    return __builtin_amdgcn_mfma_f32_16x16x32_bf16(a, b, c, 0, 0, 0);
}

// split-bf16 store: v -> [hi | lo | hi] planes of a tripled-K activation row
__device__ __forceinline__ void store3(__hip_bfloat16* p, long row, int kp, int col, float v){
    __hip_bfloat16 hi = __float2bfloat16(v);
    float lo = v - __bfloat162float(hi);
    p[row + col]        = hi;
    p[row + kp + col]   = __float2bfloat16(lo);
    p[row + 2*kp + col] = hi;
}

// ===========================================================================
// MFMA mainloop: C-tile 32m x 128n, 256 threads (4 waves), K in steps of 32.
// A: bf16 [M][lda] row-major; W: bf16 rows [N][ldb] (NT gemm).
// LDS tiles in fragment order (lane-contiguous 16B slots).
// ===========================================================================
__device__ void mfma_loop_32x128(const __hip_bfloat16* Apk, long lda, int m0,
                                 const __hip_bfloat16* Wrows, long ldb,
                                 int KS, char* sA, char* sB, floatx4 acc[2][2])
{
    const int tid = threadIdx.x, l = tid & 63, w = tid >> 6;
    const char* Ab = (const char*)(Apk + (long)(m0 + (tid>>6)*16 + (tid&15))*lda
                                   + (long)(((tid&63)>>4)*8));
    int r0 = tid >> 2, qd = tid & 3;
    const char* Bb0 = (const char*)(Wrows + (long)r0*ldb + qd*8);
    const char* Bb1 = (const char*)(Wrows + (long)(r0+64)*ldb + qd*8);
    int4* sAv = (int4*)sA;
    int4* sBv = (int4*)sB;
    int bs0 = (r0>>4)*64 + (r0&15) + (qd<<4);
    int bs1 = bs0 + 256;
    int4 aR, bR0, bR1;
    if (tid < 128) aR = *(const int4*)Ab;
    bR0 = *(const int4*)Bb0; bR1 = *(const int4*)Bb1;
    for (int ks = 0; ks < KS; ++ks) {
        __syncthreads();
        if (tid < 128) sAv[tid] = aR;
        sBv[bs0] = bR0; sBv[bs1] = bR1;
        __syncthreads();
        long off = (long)(ks+1)*64;
        if (ks+1 < KS) {
            if (tid < 128) aR = *(const int4*)(Ab + off);
            bR0 = *(const int4*)(Bb0 + off); bR1 = *(const int4*)(Bb1 + off);
        }
        const short8* A8 = (const short8*)sA;
        const short8* B8 = (const short8*)sB;
        short8 a0 = A8[l], a1 = A8[64+l];
        short8 b0 = B8[(w*2)*64 + l], b1 = B8[(w*2+1)*64 + l];
        acc[0][0] = mfma16(a0,b0,acc[0][0]);
        acc[0][1] = mfma16(a0,b1,acc[0][1]);
        acc[1][0] = mfma16(a1,b0,acc[1][0]);
        acc[1][1] = mfma16(a1,b1,acc[1][1]);
    }
}

// Generic 32x128 tile: D = A@W^T + b1 + b2 -> fp32 or bf16 out
__device__ void gemm_tile(const __hip_bfloat16* Apk, long lda, int m0,
                          const __hip_bfloat16* Wpk, long ldb, int n0,
                          const float* b1, const float* b2,
                          void* Cout, long ldc, int KS, int out_bf16, char* smem)
{
    char* sA = smem; char* sB = smem + 2048;
    floatx4 z4 = {0.f,0.f,0.f,0.f};
    floatx4 acc[2][2] = {{z4,z4},{z4,z4}};
    mfma_loop_32x128(Apk, lda, m0, Wpk + (long)n0*ldb, ldb, KS, sA, sB, acc);
    const int tid = threadIdx.x, l = tid&63, w = tid>>6;
    for (int i = 0; i < 2; ++i)
      for (int jn = 0; jn < 2; ++jn) {
        int n = n0 + (w*2+jn)*16 + (l&15);
        float bb = (b1? b1[n]:0.f) + (b2? b2[n]:0.f);
        for (int r = 0; r < 4; ++r) {
            int m = m0 + i*16 + ((l>>4)<<2) + r;
            float v = acc[i][jn][r] + bb;
            if (out_bf16) ((__hip_bfloat16*)Cout)[(long)m*ldc + n] = __float2bfloat16(v);
            else          ((float*)Cout)[(long)m*ldc + n] = v;
        }
      }
}

__global__ __launch_bounds__(256)
void gemm_mfma_k(const __hip_bfloat16* Apk, long lda,
                 const __hip_bfloat16* Bpk, long ldb,
                 const float* b1, const float* b2,
                 void* Cout, long ldc, int KS, int out_bf16)
{
    __shared__ __align__(16) char smem[10240];
    gemm_tile(Apk, lda, blockIdx.x*32, Bpk, ldb, blockIdx.y*128, b1, b2,
              Cout, ldc, KS, out_bf16, smem);
}

// ===========================================================================
// Gates GEMM (packed, gate-interleaved rows, tripled-K) + fused LSTM cell.
// Block: 32 batch x 128 packed-cols (= 32 units x 4 gates). smem >= 18432.
// ===========================================================================
__device__ void gates_cell_tile(const __hip_bfloat16* Apk, long lda,
                                const __hip_bfloat16* Wpk, long ldw,
                                const float* bpk, float* c_state, float* h_f32,
                                __hip_bfloat16* d1, int d1ld, int d1kp, int d1off,
                                __hip_bfloat16* d2, int d2ld, int d2kp, int d2off,
                                __hip_bfloat16* d3, int d3ld, int d3kp, int d3off,
                                int KS, int m0, int jb, char* smem)
{
    char* sA = smem; char* sB = smem + 2048;
    floatx4 z4 = {0.f,0.f,0.f,0.f};
    floatx4 acc[2][2] = {{z4,z4},{z4,z4}};
    mfma_loop_32x128(Apk, lda, m0, Wpk + (long)jb*128*ldw, ldw, KS, sA, sB, acc);
    __syncthreads();
    float (*gl)[36] = (float(*)[36])smem;   // 128x36 fp32, overlaps sA/sB
    const int tid = threadIdx.x, l = tid&63, w = tid>>6;
    for (int i = 0; i < 2; ++i)
      for (int jn = 0; jn < 2; ++jn) {
        int nl = (w*2+jn)*16 + (l&15);
        int mb = i*16 + ((l>>4)<<2);
        *(floatx4*)&gl[nl][mb] = acc[i][jn];
      }
    __syncthreads();
    for (int idx = tid; idx < 1024; idx += 256) {
        int u = idx >> 5, m = idx & 31;
        float g0 = gl[u   ][m] + bpk[jb*128 + u];
        float g1 = gl[32+u][m] + bpk[jb*128 + 32 + u];
        float g2 = gl[64+u][m] + bpk[jb*128 + 64 + u];
        float g3 = gl[96+u][m] + bpk[jb*128 + 96 + u];
        int bg = m0 + m, un = jb*32 + u;
        long ci = (long)bg*512 + un;
        float c2 = sigmoidf_(g1)*c_state[ci] + sigmoidf_(g0)*tanhf(g2);
        float h2 = sigmoidf_(g3)*tanhf(c2);
        c_state[ci] = c2;
        if (h_f32) h_f32[ci] = h2;
        store3(d1, (long)bg*d1ld, d1kp, d1off + un, h2);
        if (d2) store3(d2, (long)bg*d2ld, d2kp, d2off + un, h2);
        if (d3) store3(d3, (long)bg*d3ld, d3kp, d3off + un, h2);
    }
}

// ===========================================================================
// Alignment attention (per-batch block): fp32 logits, softmax, sent.
// sent -> Adec (tripled) cols 104..359
// ===========================================================================
__device__ void align_fn(int b, const float* dp, const float* langpre,
                         const float* hlang, const float* w2,
                         __hip_bfloat16* Ad_p, char* smem)
{
    float* dps    = (float*)smem;     // 512
    float* red    = dps + 512;        // 256
    float* logits = red + 256;        // 32
    float* smv    = logits + 32;      // 32
    float* ssum   = smv + 32;         // 1
    const int tid = threadIdx.x;
    for (int k = tid; k < 512; k += 256) dps[k] = dp[(long)b*512 + k];
    __syncthreads();
    {
        int ll = tid >> 3, part = tid & 7;
        const float* lp = langpre + ((long)b*32 + ll)*512 + part*64;
        const float* dpp = dps + part*64;
        const float* w2p = w2 + part*64;
        float acc = 0.f;
        for (int a = 0; a < 64; ++a)
            acc += tanhf(dpp[a] + lp[a]) * w2p[a];
        red[tid] = acc;
    }
    __syncthreads();
    if ((tid & 7) == 0) {
        float s = 0.f;
        for (int p2 = 0; p2 < 8; ++p2) s += red[tid + p2];
        logits[tid >> 3] = s;
    }
    __syncthreads();
    if (tid == 0) {
        float mx = logits[0];
        for (int i = 1; i < 32; ++i) mx = fmaxf(mx, logits[i]);
        float s = 0.f;
        for (int i = 0; i < 32; ++i) { float e = expf(logits[i]-mx); smv[i]=e; s+=e; }
        ssum[0] = s;
    }
    __syncthreads();
    {
        float acc = 0.f;
        const float* hl = hlang + (long)b*32*256 + tid;
        for (int i = 0; i < 32; ++i) acc += smv[i]*hl[(long)i*256];
        store3(Ad_p, (long)b*2688, 896, 104 + tid, acc/ssum[0]);
    }
}

// K_E: blocks 0-63 enc gates+cell; blocks 64-191 alignment
__global__ __launch_bounds__(256)
void enc_align_k(const __hip_bfloat16* Ae_p, const __hip_bfloat16* Wenc,
                 const float* benc, float* c_enc,
                 __hip_bfloat16* Ae_q, __hip_bfloat16* Ahe3,
                 const float* dp, const float* langpre, const float* hlang,
                 const float* w2, __hip_bfloat16* Ad_p)
{
    __shared__ __align__(16) char smem[18432];
    int bid = blockIdx.x;
    if (bid < 64) {
        int m0 = ((bid>>4)&3)*32, jb = bid & 15;
        gates_cell_tile(Ae_p, 3552, Wenc, 3552, benc, c_enc, nullptr,
                        Ae_q, 3552, 1184, 664,  Ahe3, 1536, 512, 0,
                        nullptr, 0, 0, 0,  111, m0, jb, smem);
    } else {
        align_fn(bid-64, dp, langpre, hlang, w2, Ad_p, smem);
    }
}

// K_D: dec gates+cell
__global__ __launch_bounds__(256)
void dec_k(const __hip_bfloat16* Ad_p, const __hip_bfloat16* Wdec, const float* bdec,
           float* c_dec, float* h_dec,
           __hip_bfloat16* Ae_q, __hip_bfloat16* Ad_q, __hip_bfloat16* Ahd3)
{
    __shared__ __align__(16) char smem[18432];
    int m0 = ((blockIdx.x>>4)&3)*32, jb = blockIdx.x & 15;
    gates_cell_tile(Ad_p, 2688, Wdec, 2688, bdec, c_dec, h_dec,
                    Ae_q, 3552, 1184, 152,  Ad_q, 2688, 896, 360,
                    Ahd3, 1536, 512, 0,  84, m0, jb, smem);
}

// ===========================================================================
// K_M: mu/sigma/q. 32m x 256n MFMA tile per block, grid = 4. Tripled K=1536.
// Wms3 rows: 0-99 mu_W, 128-227 sig_W, rest 0.
// ===========================================================================
__global__ __launch_bounds__(256)
void musig_k(const __hip_bfloat16* Ahe3, const __hip_bfloat16* Wms3,
             const float* mu_b, const float* sig_b,
             const float* eps, __hip_bfloat16* Ad_p)
{
    __shared__ __align__(16) char smem[36864];
    char* sA = smem; char* sB = smem + 2048;
    const int tid = threadIdx.x, l = tid & 63, w = tid >> 6;
    int m0 = blockIdx.x * 32;
    floatx4 z4 = {0.f,0.f,0.f,0.f};
    floatx4 acc[2][4] = {{z4,z4,z4,z4},{z4,z4,z4,z4}};
    const char* Ab = (const char*)(Ahe3 + (long)(m0 + (tid>>6)*16 + (tid&15))*1536
                                   + (long)(((tid&63)>>4)*8));
    int r0 = tid >> 2, qd = tid & 3;
    const char* Bb[4]; int bs[4];
    for (int kk = 0; kk < 4; ++kk) {
        int r = r0 + kk*64;
        Bb[kk] = (const char*)(Wms3 + (long)r*1536 + qd*8);
        bs[kk] = (r>>4)*64 + (r&15) + (qd<<4);
    }
    int4* sAv = (int4*)sA; int4* sBv = (int4*)sB;
    int4 aR, bR[4];
    if (tid < 128) aR = *(const int4*)Ab;
    for (int kk = 0; kk < 4; ++kk) bR[kk] = *(const int4*)Bb[kk];
    const int KS = 48;
    for (int ks = 0; ks < KS; ++ks) {
        __syncthreads();
        if (tid < 128) sAv[tid] = aR;
        for (int kk = 0; kk < 4; ++kk) sBv[bs[kk]] = bR[kk];
        __syncthreads();
        long off = (long)(ks+1)*64;
        if (ks+1 < KS) {
            if (tid < 128) aR = *(const int4*)(Ab + off);
            for (int kk = 0; kk < 4; ++kk) bR[kk] = *(const int4*)(Bb[kk] + off);
        }
        const short8* A8 = (const short8*)sA;
        const short8* B8 = (const short8*)sB;
        short8 a0 = A8[l], a1 = A8[64+l];
        for (int jn = 0; jn < 4; ++jn) {
            short8 bb = B8[(w*4+jn)*64 + l];
            acc[0][jn] = mfma16(a0,bb,acc[0][jn]);
            acc[1][jn] = mfma16(a1,bb,acc[1][jn]);
        }
    }
    __syncthreads();
    float (*gl)[36] = (float(*)[36])smem;   // 256x36
    for (int i = 0; i < 2; ++i)
      for (int jn = 0; jn < 4; ++jn) {
        int nl = (w*4+jn)*16 + (l&15);
        int mb = i*16 + ((l>>4)<<2);
        *(floatx4*)&gl[nl][mb] = acc[i][jn];
      }
    __syncthreads();
    for (int idx = tid; idx < 3200; idx += 256) {
        int o = idx >> 5, m = idx & 31;
        int bg = m0 + m;
        float mu = gl[o][m] + mu_b[o];
        float sg = expf(gl[128+o][m] + sig_b[o]);
        float q = mu + eps[(long)bg*100 + o]*sg;
        store3(Ad_p, (long)bg*2688, 896, o, q);
    }
}

// ===========================================================================
// Read-attention glimpse (per-batch block) -> r into Aenc (tripled) cols 0..149
// ===========================================================================
__device__ void glimpse_fn(int b, const float* x, const float* h_dec,
                           const float* attn_W, const float* attn_b,
                           __hip_bfloat16* Ae_q, char* smem)
{
    float* red = (float*)smem;   // 256
    float* sP  = red + 256;      // 8
    float* Fx  = sP + 8;         // 320
    float* Fy  = Fx + 320;       // 320
    float* denx= Fy + 320;       // 8
    float* deny= denx + 8;       // 8
    float* SFx = deny + 8;       // 8
    float* SFy = SFx + 8;        // 8
    float* tmp1= SFy + 8;        // 960
    const int tid = threadIdx.x;
    const float* hd = h_dec + (long)b*512;
    for (int i = 0; i < 5; ++i) {
        float p = 0.f;
        for (int k = tid; k < 512; k += 256) p += hd[k]*attn_W[i*512+k];
        red[tid] = p; __syncthreads();
        for (int st = 128; st > 0; st >>= 1) { if (tid < st) red[tid] += red[tid+st]; __syncthreads(); }
        if (tid == 0) sP[i] = red[0] + attn_b[i];
        __syncthreads();
    }
    float gx    = 32.5f*(sP[0]+1.f);
    float gy    = 32.5f*(sP[1]+1.f);
    float s2    = expf(sP[2]);
    float delta = 15.75f*expf(sP[3]);
    for (int p = tid; p < 320; p += 256) {
        int i = p >> 6, a = p & 63;
        float mux = gx + ((float)i - 3.0f)*delta;
        float muy = gy + ((float)i - 3.0f)*delta;
        float dx = (float)a - mux, dy = (float)a - muy;
        Fx[i*64+a] = expf(-dx*dx/(2.f*s2));
        Fy[i*64+a] = expf(-dy*dy/(2.f*s2));
    }
    __syncthreads();
    if (tid < 10) {
        int i = tid % 5;
        const float* F = (tid < 5) ? (Fx + i*64) : (Fy + i*64);
        float s = 0.f;
        for (int a = 0; a < 64; ++a) s += F[a];
        if (tid < 5) denx[i] = s + 1e-8f; else deny[i] = s + 1e-8f;
    }
    __syncthreads();
    for (int p = tid; p < 320; p += 256) {
        int i = p >> 6, a = p & 63;
        Fx[i*64+a] /= denx[i];
        Fy[i*64+a] /= deny[i];
    }
    __syncthreads();
    if (tid < 10) {
        int i = tid % 5;
        const float* F = (tid < 5) ? (Fx + i*64) : (Fy + i*64);
        float s = 0.f;
        for (int a = 0; a < 64; ++a) s += F[a];
        if (tid < 5) SFx[i] = s; else SFy[i] = s;
    }
    __syncthreads();
    for (int p = tid; p < 192; p += 256) {
        int cc = p / 64, yy = p - cc*64;
        const float* row = x + (long)b*12288 + cc*4096 + yy*64;
        float a0=0,a1=0,a2=0,a3=0,a4=0;
        for (int xx = 0; xx < 64; ++xx) {
            float v = row[xx];
            a0 += v*Fx[0*64+xx]; a1 += v*Fx[1*64+xx]; a2 += v*Fx[2*64+xx];
            a3 += v*Fx[3*64+xx]; a4 += v*Fx[4*64+xx];
        }
        tmp1[(cc*64+yy)*5+0]=a0; tmp1[(cc*64+yy)*5+1]=a1; tmp1[(cc*64+yy)*5+2]=a2;
        tmp1[(cc*64+yy)*5+3]=a3; tmp1[(cc*64+yy)*5+4]=a4;
    }
    __syncthreads();
    if (tid < 75) {
        int cc = tid/25, i = (tid/5)%5, j = tid%5;
        float g = 0.f;
        for (int yy = 0; yy < 64; ++yy) g += Fy[i*64+yy]*tmp1[(cc*64+yy)*5 + j];
        float gamma = expf(sP[4]);
        long ro = (long)b*3552;
        store3(Ae_q, ro, 1184, tid,      gamma*g);
        store3(Ae_q, ro, 1184, 75 + tid, gamma*(g - 0.5f*SFy[i]*SFx[j]));
    }
}

// ===========================================================================
// Write head (per-batch block), fp32 throughout
// ===========================================================================
__device__ void write_fn(int b, const float* h_dec,
                         const float* write_W, const float* write_b,
                         const float* attn_W, const float* attn_b,
                         float* outp, char* smem)
{
    float* hs  = (float*)smem;    // 512
    float* red = hs + 512;        // 256
    float* sP  = red + 256;       // 8
    float* w75 = sP + 8;          // 80
    float* Fx  = w75 + 80;        // 320
    float* Fy  = Fx + 320;        // 320
    float* denx= Fy + 320;        // 8
    float* deny= denx + 8;        // 8
    float* t2  = deny + 8;        // 960
    const int tid = threadIdx.x;
    for (int k = tid; k < 512; k += 256) hs[k] = h_dec[(long)b*512 + k];
    __syncthreads();
    for (int i = 0; i < 5; ++i) {
        float p = 0.f;
        for (int k = tid; k < 512; k += 256) p += hs[k]*attn_W[i*512+k];
        red[tid] = p; __syncthreads();
        for (int st = 128; st > 0; st >>= 1) { if (tid < st) red[tid] += red[tid+st]; __syncthreads(); }
        if (tid == 0) sP[i] = red[0] + attn_b[i];
        __syncthreads();
    }
    float gx    = 32.5f*(sP[0]+1.f);
    float gy    = 32.5f*(sP[1]+1.f);
    float s2    = expf(sP[2]);
    float delta = 15.75f*expf(sP[3]);
    float inv_g = 1.f/expf(sP[4]);
    if (tid < 75) {
        const float4* w4 = (const float4*)(write_W + (long)tid*512);
        const float4* h4 = (const float4*)hs;
        float acc = 0.f;
        for (int k = 0; k < 128; ++k) {
            float4 wv = w4[k], hv = h4[k];
            acc += wv.x*hv.x + wv.y*hv.y + wv.z*hv.z + wv.w*hv.w;
        }
        w75[tid] = acc + write_b[tid];
    }
    for (int p = tid; p < 320; p += 256) {
        int i = p >> 6, a = p & 63;
        float mux = gx + ((float)i - 3.0f)*delta;
        float muy = gy + ((float)i - 3.0f)*delta;
        float dx = (float)a - mux, dy = (float)a - muy;
        Fx[i*64+a] = expf(-dx*dx/(2.f*s2));
        Fy[i*64+a] = expf(-dy*dy/(2.f*s2));
    }
    __syncthreads();
    if (tid < 10) {
        int i = tid % 5;
        const float* F = (tid < 5) ? (Fx + i*64) : (Fy + i*64);
        float s = 0.f;
        for (int a = 0; a < 64; ++a) s += F[a];
        if (tid < 5) denx[i] = s + 1e-8f; else deny[i] = s + 1e-8f;
    }
    __syncthreads();
    for (int p = tid; p < 320; p += 256) {
        int i = p >> 6, a = p & 63;
        Fx[i*64+a] /= denx[i];
        Fy[i*64+a] /= deny[i];
    }
    __syncthreads();
    for (int p = tid; p < 960; p += 256) {
        int cc = p / 320, rem = p - cc*320;
        int i = rem / 64, xx = rem - i*64;
        float acc = 0.f;
        for (int j = 0; j < 5; ++j) acc += w75[cc*25 + i*5 + j]*Fx[j*64+xx];
        t2[(cc*5+i)*64+xx] = acc;
    }
    __syncthreads();
    float* ob = outp + (long)b*12288;
    for (int p = tid; p < 12288; p += 256) {
        int cc = p >> 12, yy = (p >> 6) & 63, xx = p & 63;
        float acc = 0.f;
        for (int i = 0; i < 5; ++i) acc += Fy[i*64+yy]*t2[(cc*5+i)*64+xx];
        ob[p] = acc*inv_g;
    }
}

// K_G: blocks 0-127 glimpse(t+1); 128-143 dp GEMM(t+1); 144-271 write(t)
__global__ __launch_bounds__(256)
void wgd_k(const float* x, const float* h_dec,
           const float* attn_W, const float* attn_b,
           const float* write_W, const float* write_b,
           float* outp,
           __hip_bfloat16* Ae_q,
           const __hip_bfloat16* Ahd3, const __hip_bfloat16* W1dec3,
           float* dp)
{
    __shared__ __align__(16) char smem[10240];
    int bid = blockIdx.x;
    if (bid < 128) {
        glimpse_fn(bid, x, h_dec, attn_W, attn_b, Ae_q, smem);
    } else if (bid < 144) {
        int t = bid - 128;
        gemm_tile(Ahd3, 1536, (t&3)*32, W1dec3, 1536, (t>>2)*128,
                  nullptr, nullptr, dp, 512, 48, 0, smem);
    } else {
        if (outp) write_fn(bid-144, h_dec, write_W, write_b, attn_W, attn_b, outp, smem);
    }
}

// ===========================================================================
// Language bi-LSTM step (fp32 throughout; writes hlang fp32)
// ===========================================================================
__global__ __launch_bounds__(128)
void lang_step_k(int s, const float* xpf, const float* xpb,
                 const float* Whh_f, const float* Whh_b,
                 float* hf, float* cf, float* hb, float* cb,
                 float* hlang)
{
    const int b   = blockIdx.x & 127;
    const int dir = blockIdx.x >> 7;
    const int tid = threadIdx.x;
    const int l   = dir ? (31 - s) : s;
    const float* xp = (dir ? xpb : xpf) + ((long)b*32 + l)*512;
    const float* Whh = dir ? Whh_b : Whh_f;
    float* h = (dir ? hb : hf) + b*128;
    float* c = (dir ? cb : cf) + b*128;
    __shared__ __align__(16) float hs[128];
    __shared__ float gs[512];
    hs[tid] = h[tid];
    __syncthreads();
    const float4* hs4 = (const float4*)hs;
    for (int j = tid; j < 512; j += 128) {
        float acc = xp[j];
        const float4* w4 = (const float4*)(Whh + (long)j*128);
        for (int k = 0; k < 32; ++k) {
            float4 hv = hs4[k], wv = w4[k];
            acc += hv.x*wv.x + hv.y*wv.y + hv.z*wv.z + hv.w*wv.w;
        }
        gs[j] = acc;
    }
    __syncthreads();
    float c2 = sigmoidf_(gs[128+tid])*c[tid] + sigmoidf_(gs[tid])*tanhf(gs[256+tid]);
    float h2 = sigmoidf_(gs[384+tid])*tanhf(c2);
    c[tid] = c2; h[tid] = h2;
    hlang[((long)b*32 + l)*256 + dir*128 + tid] = h2;
}

// ===========================================================================
// Packing kernels: fp32 -> tripled split-bf16
//   activations: [hi | lo | hi]; weights: [hi | hi | lo]
// ===========================================================================
__global__ void pack_a3_k(__hip_bfloat16* dst, int KP, long N,
                          const float* src, int ld, int K1)
{
    long idx = (long)blockIdx.x*256 + threadIdx.x;
    int K3 = 3*KP;
    long tot = N*K3;
    if (idx >= tot) return;
    long n = idx / K3; int k3 = (int)(idx - n*K3);
    int plane = k3 / KP, k = k3 - plane*KP;
    float v = (k < K1) ? src[n*ld + k] : 0.f;
    __hip_bfloat16 hi = __float2bfloat16(v);
    float lo = v - __bfloat162float(hi);
    dst[idx] = (plane==1) ? __float2bfloat16(lo) : hi;
}

__global__ void pack_w3_k(__hip_bfloat16* dst, int KP, long N,
                          const float* src, int ld, int K1)
{
    long idx = (long)blockIdx.x*256 + threadIdx.x;
    int K3 = 3*KP;
    long tot = N*K3;
    if (idx >= tot) return;
    long n = idx / K3; int k3 = (int)(idx - n*K3);
    int plane = k3 / KP, k = k3 - plane*KP;
    float v = (k < K1) ? src[n*ld + k] : 0.f;
    __hip_bfloat16 hi = __float2bfloat16(v);
    float lo = v - __bfloat162float(hi);
    dst[idx] = (plane==2) ? __float2bfloat16(lo) : hi;
}

__global__ void pack_gates3_k(__hip_bfloat16* dst, int KP,
                              const float* Wih, int ldih, int K1, int off2, int K2, int off3,
                              const float* Whh)
{
    long idx = (long)blockIdx.x*256 + threadIdx.x;
    int K3 = 3*KP;
    long tot = 2048L*K3;
    if (idx >= tot) return;
    long p = idx / K3; int k3 = (int)(idx - p*K3);
    int plane = k3 / KP, k = k3 - plane*KP;
    int j = (int)(p >> 7), g = (int)((p>>5)&3), uu = (int)(p&31);
    int n = g*512 + j*32 + uu;
    float v = 0.f;
    if (k < K1)                          v = Wih[(long)n*ldih + k];
    else if (k >= off2 && k < off2+K2)   v = Wih[(long)n*ldih + K1 + (k-off2)];
    else if (k >= off3 && k < off3+512)  v = Whh[(long)n*512 + (k-off3)];
    __hip_bfloat16 hi = __float2bfloat16(v);
    float lo = v - __bfloat162float(hi);
    dst[idx] = (plane==2) ? __float2bfloat16(lo) : hi;
}

__global__ void pack_gbias_k(float* dst, const float* bih, const float* bhh)
{
    int p = blockIdx.x*256 + threadIdx.x;
    if (p >= 2048) return;
    int j = p >> 7, g = (p>>5)&3, uu = p&31;
    int n = g*512 + j*32 + uu;
    dst[p] = bih[n] + bhh[n];
}

__global__ void pack_musig3_k(__hip_bfloat16* dst, const float* mu_W, const float* sig_W)
{
    long idx = (long)blockIdx.x*256 + threadIdx.x;
    if (idx >= 256L*1536) return;
    int p = (int)(idx / 1536), k3 = (int)(idx - (long)p*1536);
    int plane = k3 >> 9, k = k3 & 511;
    float v = 0.f;
    if (p < 100)                  v = mu_W[(long)p*512 + k];
    else if (p >= 128 && p < 228) v = sig_W[(long)(p-128)*512 + k];
    __hip_bfloat16 hi = __float2bfloat16(v);
    float lo = v - __bfloat162float(hi);
    dst[idx] = (plane==2) ? __float2bfloat16(lo) : hi;
}

// ===========================================================================
extern "C" void kernel_launch(void* const* d_in, const int* in_sizes, int n_in,
                              void* d_out, int out_size, void* d_ws, size_t ws_size,
                              hipStream_t stream)
{
    const float* x        = (const float*)d_in[0];
    const float* y        = (const float*)d_in[1];
    const float* eps_q    = (const float*)d_in[2];
    const float* enc_Wih  = (const float*)d_in[3];
    const float* enc_Whh  = (const float*)d_in[4];
    const float* enc_bih  = (const float*)d_in[5];
    const float* enc_bhh  = (const float*)d_in[6];
    const float* dec_Wih  = (const float*)d_in[7];
    const float* dec_Whh  = (const float*)d_in[8];
    const float* dec_bih  = (const float*)d_in[9];
    const float* dec_bhh  = (const float*)d_in[10];
    const float* mu_W     = (const float*)d_in[11];
    const float* mu_b     = (const float*)d_in[12];
    const float* sig_W    = (const float*)d_in[13];
    const float* sig_b    = (const float*)d_in[14];
    const float* write_W  = (const float*)d_in[15];
    const float* write_b  = (const float*)d_in[16];
    const float* align_W1 = (const float*)d_in[17];
    const float* align_b1 = (const float*)d_in[18];
    const float* align_w2 = (const float*)d_in[19];
    const float* attn_W   = (const float*)d_in[20];
    const float* attn_b   = (const float*)d_in[21];
    const float* lf_Wih   = (const float*)d_in[22];
    const float* lf_Whh   = (const float*)d_in[23];
    const float* lf_bih   = (const float*)d_in[24];
    const float* lf_bhh   = (const float*)d_in[25];
    const float* lb_Wih   = (const float*)d_in[26];
    const float* lb_Whh   = (const float*)d_in[27];
    const float* lb_bih   = (const float*)d_in[28];
    const float* lb_bhh   = (const float*)d_in[29];
    float* out = (float*)d_out;

    float* ws = (float*)d_ws;
    size_t off = 0;
    auto alloc = [&](size_t n){ float* p = ws + off; off += n; return p; };

    // ---- zeroed region ----
    float* Aenc0f = alloc(227328);   // 128x3552 bf16
    float* Aenc1f = alloc(227328);
    float* Adec0f = alloc(172032);   // 128x2688 bf16
    float* Adec1f = alloc(172032);
    float* Ahd3f  = alloc(98304);    // 128x1536 bf16 (h_dec split, for dp GEMM)
    float* Ahe3f  = alloc(98304);    // 128x1536 bf16 (h_enc split, for musig)
    float* c_enc  = alloc(65536);
    float* c_dec  = alloc(65536);
    float* h_dec  = alloc(65536);
    float* hfb    = alloc(16384);
    float* cfb    = alloc(16384);
    float* hbb    = alloc(16384);
    float* cbb    = alloc(16384);
    size_t zero_floats = off;
    // ---- persistent ----
    float* dpb      = alloc(65536);     // 128x512 fp32
    float* hlangf   = alloc(1048576);   // 4096x256 fp32
    float* hlang3f  = alloc(1572864);   // 4096x768 bf16 tripled
    float* langpre  = alloc(2097152);   // 4096x512 fp32
    float* W1lang3f = alloc(196608);    // 512x768 bf16
    float* W1dec3f  = alloc(393216);    // 512x1536 bf16
    // ---- shared region (phase1 / phase2 overlap) ----
    float* shared = alloc(6651904);
    // phase1 layout
    float* y3f   = shared;               // 4096x960 bf16  = 1966080 f
    float* Wlf3f = shared + 1966080;     // 512x960 bf16   = 245760 f
    float* Wlb3f = Wlf3f + 245760;
    float* xpf   = Wlb3f + 245760;       // 4096x512 fp32  = 2097152 f
    float* xpb   = xpf + 2097152;
    // phase2 layout (same region, used after lang steps)
    float* Wenc3f = shared;              // 2048x3552 bf16 = 3637248 f
    float* Wdec3f = Wenc3f + 3637248;    // 2048x2688 bf16 = 2752512 f
    float* Wms3f  = Wdec3f + 2752512;    // 256x1536 bf16  = 196608 f
    float* benc   = Wms3f + 196608;      // 2048 f
    float* bdec   = benc + 2048;         // 2048 f

    __hip_bfloat16* Aenc0 = (__hip_bfloat16*)Aenc0f;
    __hip_bfloat16* Aenc1 = (__hip_bfloat16*)Aenc1f;
    __hip_bfloat16* Adec0 = (__hip_bfloat16*)Adec0f;
    __hip_bfloat16* Adec1 = (__hip_bfloat16*)Adec1f;
    __hip_bfloat16* Ahd3  = (__hip_bfloat16*)Ahd3f;
    __hip_bfloat16* Ahe3  = (__hip_bfloat16*)Ahe3f;
    __hip_bfloat16* hlang3= (__hip_bfloat16*)hlang3f;
    __hip_bfloat16* W1lang3=(__hip_bfloat16*)W1lang3f;
    __hip_bfloat16* W1dec3= (__hip_bfloat16*)W1dec3f;
    __hip_bfloat16* y3    = (__hip_bfloat16*)y3f;
    __hip_bfloat16* Wlf3  = (__hip_bfloat16*)Wlf3f;
    __hip_bfloat16* Wlb3  = (__hip_bfloat16*)Wlb3f;
    __hip_bfloat16* Wenc3 = (__hip_bfloat16*)Wenc3f;
    __hip_bfloat16* Wdec3 = (__hip_bfloat16*)Wdec3f;
    __hip_bfloat16* Wms3  = (__hip_bfloat16*)Wms3f;

    hipMemsetAsync(ws, 0, zero_floats*sizeof(float), stream);

    // ---- phase 1: language bi-LSTM (fp32 recurrence, split-bf16 GEMMs) ----
    pack_a3_k<<<(4096L*960+255)/256,256,0,stream>>>(y3, 320, 4096, y, 300, 300);
    pack_w3_k<<<(512L*960+255)/256,256,0,stream>>>(Wlf3, 320, 512, lf_Wih, 300, 300);
    pack_w3_k<<<(512L*960+255)/256,256,0,stream>>>(Wlb3, 320, 512, lb_Wih, 300, 300);
    pack_w3_k<<<(512L*768+255)/256,256,0,stream>>>(W1lang3, 256, 512, align_W1+512, 768, 256);
    pack_w3_k<<<(512L*1536+255)/256,256,0,stream>>>(W1dec3, 512, 512, align_W1, 768, 512);
    gemm_mfma_k<<<dim3(128,4),256,0,stream>>>(y3, 960, Wlf3, 960, lf_bih, lf_bhh, xpf, 512, 30, 0);
    gemm_mfma_k<<<dim3(128,4),256,0,stream>>>(y3, 960, Wlb3, 960, lb_bih, lb_bhh, xpb, 512, 30, 0);
    for (int s = 0; s < 32; ++s)
        lang_step_k<<<256,128,0,stream>>>(s, xpf, xpb, lf_Whh, lb_Whh, hfb, cfb, hbb, cbb, hlangf);
    pack_a3_k<<<(4096L*768+255)/256,256,0,stream>>>(hlang3, 256, 4096, hlangf, 256, 256);
    gemm_mfma_k<<<dim3(128,4),256,0,stream>>>(hlang3, 768, W1lang3, 768, align_b1, nullptr, langpre, 512, 24, 0);

    // ---- phase 2 weight packs (shared region reuse: phase1 buffers dead) ----
    pack_gates3_k<<<(2048L*10656+255)/256,256,0,stream>>>(Wenc3, 1184, enc_Wih, 662, 150, 152, 512, 664, enc_Whh);
    pack_gates3_k<<<(2048L*8064+255)/256,256,0,stream>>>(Wdec3, 896, dec_Wih, 356, 100, 104, 256, 360, dec_Whh);
    pack_gbias_k<<<8,256,0,stream>>>(benc, enc_bih, enc_bhh);
    pack_gbias_k<<<8,256,0,stream>>>(bdec, dec_bih, dec_bhh);
    pack_musig3_k<<<(256L*1536+255)/256,256,0,stream>>>(Wms3, mu_W, sig_W);

    // ---- priming: glimpse + dp for t=0 (h_dec = 0, Ahd3 = 0 -> dp = 0) ----
    wgd_k<<<272,256,0,stream>>>(x, h_dec, attn_W, attn_b, write_W, write_b,
                                nullptr, Aenc0, Ahd3, W1dec3, dpb);

    for (int t = 0; t < 32; ++t) {
        int p = t & 1;
        __hip_bfloat16* Ae_p = p ? Aenc1 : Aenc0;
        __hip_bfloat16* Ae_q = p ? Aenc0 : Aenc1;
        __hip_bfloat16* Ad_p = p ? Adec1 : Adec0;
        __hip_bfloat16* Ad_q = p ? Adec0 : Adec1;
        enc_align_k<<<192,256,0,stream>>>(Ae_p, Wenc3, benc, c_enc, Ae_q, Ahe3,
                                          dpb, langpre, hlangf, align_w2, Ad_p);
        musig_k<<<4,256,0,stream>>>(Ahe3, Wms3, mu_b, sig_b,
                                    eps_q + (long)t*12800, Ad_p);
        dec_k<<<64,256,0,stream>>>(Ad_p, Wdec3, bdec, c_dec, h_dec, Ae_q, Ad_q, Ahd3);
        wgd_k<<<272,256,0,stream>>>(x, h_dec, attn_W, attn_b, write_W, write_b,
                                    out + (long)t*128*12288, Ae_q, Ahd3, W1dec3, dpb);
    }
}